// Round 10
// baseline (1169.234 us; speedup 1.0000x reference)
//
#include <hip/hip_runtime.h>
#include <math.h>

// ---------------------------------------------------------------------------
// Fused MoE top-2 router, MI355X (gfx950) — round 10.
// R9: sched_barrier pins + 128-VGPR ceiling -> scratch spill (WRITE 31MB).
// Reverted. R8's structure was right but ran 2 waves/SIMD: sunk x-loads give
// each wave ~36% duty -> 2 waves can't fill the SIMD. R10: half-size W stage
// (64KB, SECK=256) -> 2 blocks/CU -> 4 waves/SIMD (1.45x oversubscribed ->
// stalls covered). Block does 2 sequential stages into the same acc, so the
// slab layout (kq=8, 16.8MB ws, proven) is unchanged. 3 barriers/block.
// launch_bounds(512,4) caps VGPR at 128 >= R8's measured 104 live.
// ---------------------------------------------------------------------------

#define NT 8192
#define ND 4096
#define NE 64
#define BK 64             // k floats per chunk
#define SECK2 256         // k floats per resident stage (64 KiB)
#define SLAB_OFF 512      // ws[0..129] scalars; slabs after

__device__ __forceinline__ void gload16(const float* g, float* l) {
    __builtin_amdgcn_global_load_lds(
        (const __attribute__((address_space(1))) void*)g,
        (__attribute__((address_space(3))) void*)l, 16, 0, 0);
}

#define LOADX(dst, off)                                                      \
    {                                                                        \
        _Pragma("unroll")                                                    \
        for (int t = 0; t < 8; t++)                                          \
            dst[t] = *reinterpret_cast<const float4*>(                       \
                xp + (size_t)t * ND + (off));                                \
    }

#define COMP(xv, wptr, wstride)                                              \
    {                                                                        \
        float4 wv[8];                                                        \
        _Pragma("unroll")                                                    \
        for (int e = 0; e < 8; e++)                                          \
            wv[e] = *reinterpret_cast<const float4*>((wptr) + e * (wstride));\
        _Pragma("unroll")                                                    \
        for (int e = 0; e < 8; e++) {                                        \
            _Pragma("unroll")                                                \
            for (int t = 0; t < 8; t++) {                                    \
                float a = acc[t][e];                                         \
                a = fmaf(xv[t].x, wv[e].x, a);                               \
                a = fmaf(xv[t].y, wv[e].y, a);                               \
                a = fmaf(xv[t].z, wv[e].z, a);                               \
                a = fmaf(xv[t].w, wv[e].w, a);                               \
                acc[t][e] = a;                                               \
            }                                                                \
        }                                                                    \
    }

#define KREDUCE_AND_SLAB()                                                   \
    {                                                                        \
        _Pragma("unroll")                                                    \
        for (int t = 0; t < 8; t++)                                          \
            _Pragma("unroll")                                                \
            for (int e = 0; e < 8; e++) {                                    \
                float v = acc[t][e];                                         \
                v += __shfl_xor(v, 1);                                       \
                v += __shfl_xor(v, 2);                                       \
                v += __shfl_xor(v, 4);                                       \
                acc[t][e] = v;                                               \
            }                                                                \
        _Pragma("unroll")                                                    \
        for (int t = 0; t < 8; t++) {                                        \
            if (ks == t) {                                                   \
                *reinterpret_cast<float4*>(slab + (size_t)t * NE + eg * 8) = \
                    make_float4(acc[t][0], acc[t][1], acc[t][2], acc[t][3]); \
                *reinterpret_cast<float4*>(slab + (size_t)t * NE + eg * 8 + 4) = \
                    make_float4(acc[t][4], acc[t][5], acc[t][6], acc[t][7]); \
            }                                                                \
        }                                                                    \
    }

// ---- primary: resident-W (2 x 64KB stages), 4 waves/SIMD, kq = 8 ---------
__global__ __launch_bounds__(512, 4)
void pass1_res(const float* __restrict__ x, const float* __restrict__ W,
               float* __restrict__ ws)
{
    __shared__ float wres[NE * SECK2];   // 64 KiB -> 2 blocks/CU

    const int tid  = threadIdx.x;
    const int wave = tid >> 6;
    const int lane = tid & 63;
    const int eg   = lane >> 3;          // expert octet 0..7
    const int ks   = lane & 7;           // k slice 0..7 (x 4 floats)

    const int bq   = blockIdx.x >> 7;    // k-pair id 0..7 (512 k each)
    const int tb   = blockIdx.x & 127;   // token block (64 tokens)
    const int tok0 = tb * 64 + wave * 8;

    float acc[8][8];
    #pragma unroll
    for (int t = 0; t < 8; t++)
        #pragma unroll
        for (int e = 0; e < 8; e++) acc[t][e] = 0.f;

    #pragma unroll 1
    for (int st = 0; st < 2; ++st) {
        const int k0 = bq * 512 + st * SECK2;
        if (st) __syncthreads();          // all waves done with prev stage

        // stage 64KB of W: 4096 float4 slots / 512 thr = 8 each
        #pragma unroll
        for (int r = 0; r < 8; r++) {
            int s = r * 512 + tid;        // 0..4095
            gload16(W + (size_t)(s >> 6) * ND + k0 + (s & 63) * 4,
                    &wres[s << 2]);
        }

        const float* xp = x + (size_t)tok0 * ND + k0 + ks * 4;
        float4 xa[8], xb[8];
        LOADX(xa, 0);                     // overlap the staging drain
        LOADX(xb, 32);
        __syncthreads();                  // wres ready

        const float* wsec = &wres[(eg * 8) * SECK2 + ks * 4];
        #pragma unroll 1
        for (int c = 0; c < SECK2 / BK; ++c) {     // 4 chunks, no barriers
            COMP(xa, wsec + c * BK, SECK2);
            if (c + 1 < SECK2 / BK) LOADX(xa, (c + 1) * BK);
            COMP(xb, wsec + c * BK + 32, SECK2);
            if (c + 1 < SECK2 / BK) LOADX(xb, (c + 1) * BK + 32);
        }
    }

    float* slab = ws + SLAB_OFF + ((size_t)bq * NT + tok0) * NE;
    KREDUCE_AND_SLAB();
}

// ---- fallback: R6 double-buffered W (used only if ws too small) ----------
__global__ __launch_bounds__(256, 2)
void pass1_dbuf(const float* __restrict__ x, const float* __restrict__ W,
                float* __restrict__ ws, int kq_bits, int nchunk)
{
    __shared__ float wbuf[2][NE * BK];

    const int tid  = threadIdx.x;
    const int wave = tid >> 6;
    const int lane = tid & 63;
    const int eg   = lane >> 3;
    const int ks   = lane & 7;

    const int bq   = blockIdx.x >> 8;
    const int tb   = blockIdx.x & 255;
    const int tok0 = tb * 32 + wave * 8;
    const int k0   = bq * (ND >> kq_bits);

    float acc[8][8];
    #pragma unroll
    for (int t = 0; t < 8; t++)
        #pragma unroll
        for (int e = 0; e < 8; e++) acc[t][e] = 0.f;

    const float* xp = x + (size_t)tok0 * ND + k0 + ks * 4;

    #pragma unroll
    for (int r = 0; r < 4; r++) {
        int s = r * 256 + tid;
        gload16(W + (size_t)(s >> 4) * ND + k0 + (s & 15) * 4, &wbuf[0][s << 2]);
    }
    float4 xa[8], xb[8];
    LOADX(xa, 0);
    __syncthreads();

    #pragma unroll 1
    for (int c = 0; c < nchunk; ++c) {
        const int b = c & 1;
        if (c + 1 < nchunk) {
            const int koff = k0 + (c + 1) * BK;
            #pragma unroll
            for (int r = 0; r < 4; r++) {
                int s = r * 256 + tid;
                gload16(W + (size_t)(s >> 4) * ND + koff + (s & 15) * 4,
                        &wbuf[b ^ 1][s << 2]);
            }
        }
        LOADX(xb, c * BK + 32);
        COMP(xa, &wbuf[b][(eg * 8) * BK + ks * 4], BK);
        if (c + 1 < nchunk) LOADX(xa, (c + 1) * BK);
        COMP(xb, &wbuf[b][(eg * 8) * BK + 32 + ks * 4], BK);
        __syncthreads();
    }

    float* slab = ws + SLAB_OFF + ((size_t)bq * NT + tok0) * NE;
    KREDUCE_AND_SLAB();
}

__global__ __launch_bounds__(128)
void pass2(float* __restrict__ ws, float* __restrict__ out, int kq)
{
    __shared__ float imp_s[NE];
    __shared__ float load_s[NE];
    const int tid  = threadIdx.x;
    const int lane = tid & 63;
    if (tid < NE) { imp_s[tid] = 0.f; load_s[tid] = 0.f; }
    __syncthreads();

    const int tok = blockIdx.x * 128 + tid;
    float lgv[NE];
    {
        const float* p0 = ws + SLAB_OFF + (size_t)tok * NE;
        #pragma unroll
        for (int e4 = 0; e4 < 16; e4++) {
            float4 v = *reinterpret_cast<const float4*>(p0 + e4 * 4);
            lgv[e4*4+0] = v.x; lgv[e4*4+1] = v.y;
            lgv[e4*4+2] = v.z; lgv[e4*4+3] = v.w;
        }
        for (int q = 1; q < kq; q++) {
            const float* pq = ws + SLAB_OFF + ((size_t)q * NT + tok) * NE;
            #pragma unroll
            for (int e4 = 0; e4 < 16; e4++) {
                float4 v = *reinterpret_cast<const float4*>(pq + e4 * 4);
                lgv[e4*4+0] += v.x; lgv[e4*4+1] += v.y;
                lgv[e4*4+2] += v.z; lgv[e4*4+3] += v.w;
            }
        }
    }

    float m = -3.0e38f;
    #pragma unroll
    for (int e = 0; e < NE; e++) m = fmaxf(m, lgv[e]);
    float se = 0.f, ssum = 0.f;
    #pragma unroll
    for (int e = 0; e < NE; e++) { ssum += lgv[e]; se += __expf(lgv[e] - m); }
    const float lse = m + __logf(se);
    const float inv = 1.f / se;

    #pragma unroll
    for (int e = 0; e < NE; e++) lgv[e] = __expf(lgv[e] - m) * inv;

    float v1 = -3.0e38f, v2 = -3.0e38f;
    int   i1 = 0, i2 = 0;
    #pragma unroll
    for (int e = 0; e < NE; e++) {
        const float v = lgv[e];
        if (v > v1)      { v2 = v1; i2 = i1; v1 = v; i1 = e; }
        else if (v > v2) { v2 = v;  i2 = e; }
    }
    const float dn = fmaxf(v1 + v2, 1e-9f);

    out[2 * tok]              = (float)i1;
    out[2 * tok + 1]          = (float)i2;
    out[2 * NT + 2 * tok]     = v1 / dn;
    out[2 * NT + 2 * tok + 1] = v2 / dn;
    atomicAdd(&load_s[i1], 1.0f);

    float zv = lse * lse, sv = ssum;
    #pragma unroll
    for (int mk = 1; mk < 64; mk <<= 1) {
        zv += __shfl_xor(zv, mk);
        sv += __shfl_xor(sv, mk);
    }
    if (lane == 0) { atomicAdd(&ws[128], zv); atomicAdd(&ws[129], sv); }

    float impacc = 0.f;
    #pragma unroll
    for (int e = 0; e < NE; e++) {
        float v = lgv[e];
        #pragma unroll
        for (int mk = 1; mk < 64; mk <<= 1) v += __shfl_xor(v, mk);
        if (lane == e) impacc = v;
    }
    atomicAdd(&imp_s[lane], impacc);

    __syncthreads();
    if (tid < NE) {
        atomicAdd(&ws[tid], imp_s[tid]);
        atomicAdd(&ws[NE + tid], load_s[tid]);
    }
}

__global__ void finalize(const float* __restrict__ ws, float* __restrict__ out)
{
    const int l = threadIdx.x;   // one wave
    const float imp = ws[l];
    const float ld  = ws[NE + l];
    float is = imp, ls = ld;
    #pragma unroll
    for (int mk = 1; mk < 64; mk <<= 1) { is += __shfl_xor(is, mk); ls += __shfl_xor(ls, mk); }
    float v = (imp / fmaxf(is, 1e-9f)) * (ld / fmaxf(ls, 1e-9f));
    #pragma unroll
    for (int mk = 1; mk < 64; mk <<= 1) v += __shfl_xor(v, mk);
    if (l == 0) {
        out[4 * NT]     = (ws[128] / (float)NT) * 0.001f;        // router_z_loss
        out[4 * NT + 1] = v * (float)(NE * NE) * 0.01f;          // load_balance_loss
        out[4 * NT + 2] = ws[129] / (float)((size_t)NT * NE);    // logits_mean
    }
}

extern "C" void kernel_launch(void* const* d_in, const int* in_sizes, int n_in,
                              void* d_out, int out_size, void* d_ws, size_t ws_size,
                              hipStream_t stream) {
    const float* x = (const float*)d_in[0];
    const float* W = (const float*)d_in[1];
    float* out = (float*)d_out;
    float* ws  = (float*)d_ws;

    hipMemsetAsync(ws, 0, 130 * sizeof(float), stream);

    if (ws_size >= (SLAB_OFF + 8ull * NT * NE) * 4) {
        // resident-W path: 8 k-pairs x 128 token-blocks, 2 stages per block
        hipLaunchKernelGGL(pass1_res, dim3(8 * (NT / 64)), dim3(512), 0, stream,
                           x, W, ws);
        hipLaunchKernelGGL(pass2, dim3(NT / 128), dim3(128), 0, stream, ws, out, 8);
    } else {
        int kq_bits = 2;
        if (ws_size < (SLAB_OFF + 4ull * NT * NE) * 4) kq_bits = 1;
        if (ws_size < (SLAB_OFF + 2ull * NT * NE) * 4) kq_bits = 0;
        const int kq = 1 << kq_bits;
        const int nchunk = (ND >> kq_bits) / BK;
        hipLaunchKernelGGL(pass1_dbuf, dim3(256 * kq), dim3(256), 0, stream,
                           x, W, ws, kq_bits, nchunk);
        hipLaunchKernelGGL(pass2, dim3(NT / 128), dim3(128), 0, stream, ws, out, kq);
    }
    hipLaunchKernelGGL(finalize, dim3(1), dim3(64), 0, stream, ws, out);
}

// Round 11
// 65.917 us; speedup vs baseline: 17.7380x; 17.7380x over previous
//
#include <hip/hip_runtime.h>
#include <math.h>

// ---------------------------------------------------------------------------
// Fused MoE top-2 router, MI355X (gfx950) — round 11: MFMA via bf16 split.
// VALU path is dead: T8xE8 tile needs ~104-190 VGPR -> 2 waves/SIMD -> 40%
// VALU ceiling (R8=104us); every attempt to raise occupancy spilled (R4/9/10).
// New roofline: logits = xh*wh + xh*wl + xl*wh (bf16 splits, fp32 MFMA acc;
// dropped ll term ~2^-18 rel). MFMA work = ~2us, conversion ~6us VALU,
// kernel is HBM-bound on x: 134MB -> 21us floor.
//  - convert_w: W fp32 -> wh/wl bf16 in ws, in FRAGMENT-MAJOR order
//    (((kstep*4+nt)*64+lane)*8+j) -> pass1 stages linearly via gload16 and
//    ds_read_b128 is lane-dense = bank-conflict-free by construction.
//  - pass1_mfma: 512 blocks (kq=4 x 128 tb), 512 thr = 8 waves = 4mt x 2ng.
//    Wave: 16 tokens x 32 experts, acc = 2 x f32x4. x fp32 from global
//    (read once), in-reg convert to ah/al. W chunk (KC=64) double-buffered.
//  - pass2/finalize: proven slab reduction (slab base now after W arrays).
// ---------------------------------------------------------------------------

#define NT 8192
#define ND 4096
#define NE 64
#define NKS 32            // ksteps (of 32) per block = 1024 k (kq=4)
#define NCH 16            // chunks (2 ksteps each)
#define W_OFF 512         // float idx: wh (512KB = 131072 floats)
#define WL_OFF (W_OFF + 131072)
#define SLAB2 (W_OFF + 262144)
#define BKD 64            // fallback chunk
#define SLAB_OFF 512      // fallback slab base

typedef float f32x4 __attribute__((ext_vector_type(4)));
typedef short s16x8 __attribute__((ext_vector_type(8)));

__device__ __forceinline__ void gload16(const float* g, float* l) {
    __builtin_amdgcn_global_load_lds(
        (const __attribute__((address_space(1))) void*)g,
        (__attribute__((address_space(3))) void*)l, 16, 0, 0);
}

// ---- W pre-convert: fp32 -> bf16 hi/lo, fragment-major ---------------------
__global__ __launch_bounds__(256)
void convert_w(const float* __restrict__ W, float* __restrict__ ws)
{
    const int gid = blockIdx.x * 256 + threadIdx.x;   // 0..65535
    const int e  = gid >> 10;
    const int k0 = (gid & 1023) << 2;
    ushort* wh = (ushort*)(ws + W_OFF);
    ushort* wl = (ushort*)(ws + WL_OFF);
    const float* wr = W + (size_t)e * ND + k0;
    #pragma unroll
    for (int i = 0; i < 4; i++) {
        const int k = k0 + i;
        const float v = wr[i];
        const unsigned ub = __float_as_uint(v);
        const float lo = v - __uint_as_float(ub & 0xffff0000u);
        const unsigned lb = __float_as_uint(lo);
        const int sg = k >> 5, kb = (k >> 3) & 3, j = k & 7, nt = e >> 4;
        const size_t idx = ((size_t)(sg * 4 + nt) * 64 + (e & 15) + kb * 16) * 8 + j;
        wh[idx] = (ushort)(ub >> 16);
        wl[idx] = (ushort)(lb >> 16);
    }
}

// ---- primary: MFMA GEMM, kq=4 ---------------------------------------------
__global__ __launch_bounds__(512, 2)
void pass1_mfma(const float* __restrict__ x, float* __restrict__ ws)
{
    __shared__ ushort wlds[2][8192];   // [buf][ h:4096 | l:4096 ]  (32 KiB)

    const int tid  = threadIdx.x;
    const int wv   = tid >> 6, lane = tid & 63;
    const int mt   = wv >> 1,  ng   = wv & 1;
    const int bq   = blockIdx.x >> 7;      // k-quarter 0..3
    const int tb   = blockIdx.x & 127;
    const int tok0 = tb * 64;
    const int kb0  = bq << 10;

    const ushort* whg = (const ushort*)(ws + W_OFF);
    const ushort* wlg = (const ushort*)(ws + WL_OFF);

    f32x4 acc0 = {0.f, 0.f, 0.f, 0.f};
    f32x4 acc1 = {0.f, 0.f, 0.f, 0.f};

    // stage chunk 0 (8KB h + 8KB l; 512 thr x 2 gload16)
    {
        const size_t gb = (size_t)(bq * NKS) * 4096;   // bytes into frag arrays
        gload16((const float*)((const char*)whg + gb + tid * 16),
                (float*)&wlds[0][tid * 8]);
        gload16((const float*)((const char*)wlg + gb + tid * 16),
                (float*)&wlds[0][4096 + tid * 8]);
    }

    const float* xrow = x + (size_t)(tok0 + mt * 16 + (lane & 15)) * ND
                          + kb0 + ((lane >> 4) << 3);
    f32x4 xa0 = *(const f32x4*)(xrow);
    f32x4 xa1 = *(const f32x4*)(xrow + 4);
    __syncthreads();

    const int ntg0 = ng * 2, ntg1 = ng * 2 + 1;
    int b = 0;
    #pragma unroll 1
    for (int c = 0; c < NCH; ++c) {
        if (c + 1 < NCH) {
            const size_t gb = (size_t)(bq * NKS + (c + 1) * 2) * 4096;
            gload16((const float*)((const char*)whg + gb + tid * 16),
                    (float*)&wlds[b ^ 1][tid * 8]);
            gload16((const float*)((const char*)wlg + gb + tid * 16),
                    (float*)&wlds[b ^ 1][4096 + tid * 8]);
        }
        #pragma unroll
        for (int ksl = 0; ksl < 2; ++ksl) {
            const int kk = c * 2 + ksl;
            const f32x4 va = xa0, vb = xa1;
            if (kk + 1 < NKS) {                      // prefetch next kstep
                xa0 = *(const f32x4*)(xrow + (kk + 1) * 32);
                xa1 = *(const f32x4*)(xrow + (kk + 1) * 32 + 4);
            }
            // in-register fp32 -> bf16 hi/lo split (truncation both levels)
            union { s16x8 v; ushort u[8]; } ah, al;
            #pragma unroll
            for (int i = 0; i < 4; i++) {
                const unsigned u0 = __float_as_uint(va[i]);
                ah.u[i] = (ushort)(u0 >> 16);
                const float l0 = va[i] - __uint_as_float(u0 & 0xffff0000u);
                al.u[i] = (ushort)(__float_as_uint(l0) >> 16);
                const unsigned u1 = __float_as_uint(vb[i]);
                ah.u[4 + i] = (ushort)(u1 >> 16);
                const float l1 = vb[i] - __uint_as_float(u1 & 0xffff0000u);
                al.u[4 + i] = (ushort)(__float_as_uint(l1) >> 16);
            }
            const s16x8 bh0 = *(const s16x8*)&wlds[b][(ksl * 4 + ntg0) * 512 + lane * 8];
            const s16x8 bh1 = *(const s16x8*)&wlds[b][(ksl * 4 + ntg1) * 512 + lane * 8];
            const s16x8 bl0 = *(const s16x8*)&wlds[b][4096 + (ksl * 4 + ntg0) * 512 + lane * 8];
            const s16x8 bl1 = *(const s16x8*)&wlds[b][4096 + (ksl * 4 + ntg1) * 512 + lane * 8];
            acc0 = __builtin_amdgcn_mfma_f32_16x16x32_bf16(ah.v, bh0, acc0, 0, 0, 0);
            acc1 = __builtin_amdgcn_mfma_f32_16x16x32_bf16(ah.v, bh1, acc1, 0, 0, 0);
            acc0 = __builtin_amdgcn_mfma_f32_16x16x32_bf16(al.v, bh0, acc0, 0, 0, 0);
            acc1 = __builtin_amdgcn_mfma_f32_16x16x32_bf16(al.v, bh1, acc1, 0, 0, 0);
            acc0 = __builtin_amdgcn_mfma_f32_16x16x32_bf16(ah.v, bl0, acc0, 0, 0, 0);
            acc1 = __builtin_amdgcn_mfma_f32_16x16x32_bf16(ah.v, bl1, acc1, 0, 0, 0);
        }
        __syncthreads();
        b ^= 1;
    }

    // epilogue: C/D layout col=lane&15 (expert), row=(lane>>4)*4+r (token)
    float* slab = ws + SLAB2 + (size_t)bq * NT * NE;
    const int er = (lane >> 4) * 4;
    #pragma unroll
    for (int r = 0; r < 4; r++) {
        const int token = tok0 + mt * 16 + er + r;
        slab[(size_t)token * NE + ntg0 * 16 + (lane & 15)] = acc0[r];
        slab[(size_t)token * NE + ntg1 * 16 + (lane & 15)] = acc1[r];
    }
}

// ---- fallback: R8 VALU double-buffer path (only if ws too small) ----------
#define LOADX(dst, off)                                                      \
    {                                                                        \
        _Pragma("unroll")                                                    \
        for (int t = 0; t < 8; t++)                                          \
            dst[t] = *reinterpret_cast<const float4*>(                       \
                xp + (size_t)t * ND + (off));                                \
    }
#define COMP(xv, wptr, wstride)                                              \
    {                                                                        \
        float4 wvv[8];                                                       \
        _Pragma("unroll")                                                    \
        for (int e = 0; e < 8; e++)                                          \
            wvv[e] = *reinterpret_cast<const float4*>((wptr) + e * (wstride));\
        _Pragma("unroll")                                                    \
        for (int e = 0; e < 8; e++) {                                        \
            _Pragma("unroll")                                                \
            for (int t = 0; t < 8; t++) {                                    \
                float a = acc[t][e];                                         \
                a = fmaf(xv[t].x, wvv[e].x, a);                              \
                a = fmaf(xv[t].y, wvv[e].y, a);                              \
                a = fmaf(xv[t].z, wvv[e].z, a);                              \
                a = fmaf(xv[t].w, wvv[e].w, a);                              \
                acc[t][e] = a;                                               \
            }                                                                \
        }                                                                    \
    }

__global__ __launch_bounds__(256, 2)
void pass1_dbuf(const float* __restrict__ x, const float* __restrict__ W,
                float* __restrict__ ws, int kq_bits, int nchunk)
{
    __shared__ float wbuf[2][NE * BKD];
    const int tid  = threadIdx.x;
    const int wave = tid >> 6;
    const int lane = tid & 63;
    const int eg   = lane >> 3;
    const int ks   = lane & 7;
    const int bq   = blockIdx.x >> 8;
    const int tb   = blockIdx.x & 255;
    const int tok0 = tb * 32 + wave * 8;
    const int k0   = bq * (ND >> kq_bits);

    float acc[8][8];
    #pragma unroll
    for (int t = 0; t < 8; t++)
        #pragma unroll
        for (int e = 0; e < 8; e++) acc[t][e] = 0.f;

    const float* xp = x + (size_t)tok0 * ND + k0 + ks * 4;
    #pragma unroll
    for (int r = 0; r < 4; r++) {
        int s = r * 256 + tid;
        gload16(W + (size_t)(s >> 4) * ND + k0 + (s & 15) * 4, &wbuf[0][s << 2]);
    }
    float4 xa[8], xb[8];
    LOADX(xa, 0);
    __syncthreads();

    #pragma unroll 1
    for (int c = 0; c < nchunk; ++c) {
        const int b = c & 1;
        if (c + 1 < nchunk) {
            const int koff = k0 + (c + 1) * BKD;
            #pragma unroll
            for (int r = 0; r < 4; r++) {
                int s = r * 256 + tid;
                gload16(W + (size_t)(s >> 4) * ND + koff + (s & 15) * 4,
                        &wbuf[b ^ 1][s << 2]);
            }
        }
        LOADX(xb, c * BKD + 32);
        COMP(xa, &wbuf[b][(eg * 8) * BKD + ks * 4], BKD);
        if (c + 1 < nchunk) LOADX(xa, (c + 1) * BKD);
        COMP(xb, &wbuf[b][(eg * 8) * BKD + 32 + ks * 4], BKD);
        __syncthreads();
    }

    #pragma unroll
    for (int t = 0; t < 8; t++)
        #pragma unroll
        for (int e = 0; e < 8; e++) {
            float v = acc[t][e];
            v += __shfl_xor(v, 1);
            v += __shfl_xor(v, 2);
            v += __shfl_xor(v, 4);
            acc[t][e] = v;
        }
    float* slab = ws + SLAB_OFF + ((size_t)bq * NT + tok0) * NE;
    #pragma unroll
    for (int t = 0; t < 8; t++) {
        if (ks == t) {
            *reinterpret_cast<float4*>(slab + (size_t)t * NE + eg * 8) =
                make_float4(acc[t][0], acc[t][1], acc[t][2], acc[t][3]);
            *reinterpret_cast<float4*>(slab + (size_t)t * NE + eg * 8 + 4) =
                make_float4(acc[t][4], acc[t][5], acc[t][6], acc[t][7]);
        }
    }
}

__global__ __launch_bounds__(128)
void pass2(float* __restrict__ ws, float* __restrict__ out, int kq, int slab_base)
{
    __shared__ float imp_s[NE];
    __shared__ float load_s[NE];
    const int tid  = threadIdx.x;
    const int lane = tid & 63;
    if (tid < NE) { imp_s[tid] = 0.f; load_s[tid] = 0.f; }
    __syncthreads();

    const int tok = blockIdx.x * 128 + tid;
    float lgv[NE];
    {
        const float* p0 = ws + slab_base + (size_t)tok * NE;
        #pragma unroll
        for (int e4 = 0; e4 < 16; e4++) {
            float4 v = *reinterpret_cast<const float4*>(p0 + e4 * 4);
            lgv[e4*4+0] = v.x; lgv[e4*4+1] = v.y;
            lgv[e4*4+2] = v.z; lgv[e4*4+3] = v.w;
        }
        for (int q = 1; q < kq; q++) {
            const float* pq = ws + slab_base + ((size_t)q * NT + tok) * NE;
            #pragma unroll
            for (int e4 = 0; e4 < 16; e4++) {
                float4 v = *reinterpret_cast<const float4*>(pq + e4 * 4);
                lgv[e4*4+0] += v.x; lgv[e4*4+1] += v.y;
                lgv[e4*4+2] += v.z; lgv[e4*4+3] += v.w;
            }
        }
    }

    float m = -3.0e38f;
    #pragma unroll
    for (int e = 0; e < NE; e++) m = fmaxf(m, lgv[e]);
    float se = 0.f, ssum = 0.f;
    #pragma unroll
    for (int e = 0; e < NE; e++) { ssum += lgv[e]; se += __expf(lgv[e] - m); }
    const float lse = m + __logf(se);
    const float inv = 1.f / se;

    #pragma unroll
    for (int e = 0; e < NE; e++) lgv[e] = __expf(lgv[e] - m) * inv;

    float v1 = -3.0e38f, v2 = -3.0e38f;
    int   i1 = 0, i2 = 0;
    #pragma unroll
    for (int e = 0; e < NE; e++) {
        const float v = lgv[e];
        if (v > v1)      { v2 = v1; i2 = i1; v1 = v; i1 = e; }
        else if (v > v2) { v2 = v;  i2 = e; }
    }
    const float dn = fmaxf(v1 + v2, 1e-9f);

    out[2 * tok]              = (float)i1;
    out[2 * tok + 1]          = (float)i2;
    out[2 * NT + 2 * tok]     = v1 / dn;
    out[2 * NT + 2 * tok + 1] = v2 / dn;
    atomicAdd(&load_s[i1], 1.0f);

    float zv = lse * lse, sv = ssum;
    #pragma unroll
    for (int mk = 1; mk < 64; mk <<= 1) {
        zv += __shfl_xor(zv, mk);
        sv += __shfl_xor(sv, mk);
    }
    if (lane == 0) { atomicAdd(&ws[128], zv); atomicAdd(&ws[129], sv); }

    float impacc = 0.f;
    #pragma unroll
    for (int e = 0; e < NE; e++) {
        float v = lgv[e];
        #pragma unroll
        for (int mk = 1; mk < 64; mk <<= 1) v += __shfl_xor(v, mk);
        if (lane == e) impacc = v;
    }
    atomicAdd(&imp_s[lane], impacc);

    __syncthreads();
    if (tid < NE) {
        atomicAdd(&ws[tid], imp_s[tid]);
        atomicAdd(&ws[NE + tid], load_s[tid]);
    }
}

__global__ void finalize(const float* __restrict__ ws, float* __restrict__ out)
{
    const int l = threadIdx.x;
    const float imp = ws[l];
    const float ld  = ws[NE + l];
    float is = imp, ls = ld;
    #pragma unroll
    for (int mk = 1; mk < 64; mk <<= 1) { is += __shfl_xor(is, mk); ls += __shfl_xor(ls, mk); }
    float v = (imp / fmaxf(is, 1e-9f)) * (ld / fmaxf(ls, 1e-9f));
    #pragma unroll
    for (int mk = 1; mk < 64; mk <<= 1) v += __shfl_xor(v, mk);
    if (l == 0) {
        out[4 * NT]     = (ws[128] / (float)NT) * 0.001f;
        out[4 * NT + 1] = v * (float)(NE * NE) * 0.01f;
        out[4 * NT + 2] = ws[129] / (float)((size_t)NT * NE);
    }
}

extern "C" void kernel_launch(void* const* d_in, const int* in_sizes, int n_in,
                              void* d_out, int out_size, void* d_ws, size_t ws_size,
                              hipStream_t stream) {
    const float* x = (const float*)d_in[0];
    const float* W = (const float*)d_in[1];
    float* out = (float*)d_out;
    float* ws  = (float*)d_ws;

    hipMemsetAsync(ws, 0, 130 * sizeof(float), stream);

    const size_t need_mfma = (size_t)(SLAB2 + 4ull * NT * NE) * 4;
    if (ws_size >= need_mfma) {
        hipLaunchKernelGGL(convert_w, dim3(256), dim3(256), 0, stream, W, ws);
        hipLaunchKernelGGL(pass1_mfma, dim3(4 * 128), dim3(512), 0, stream, x, ws);
        hipLaunchKernelGGL(pass2, dim3(NT / 128), dim3(128), 0, stream,
                           ws, out, 4, SLAB2);
    } else {
        int kq_bits = 2;
        if (ws_size < (SLAB_OFF + 4ull * NT * NE) * 4) kq_bits = 1;
        if (ws_size < (SLAB_OFF + 2ull * NT * NE) * 4) kq_bits = 0;
        const int kq = 1 << kq_bits;
        const int nchunk = (ND >> kq_bits) / BKD;
        hipLaunchKernelGGL(pass1_dbuf, dim3(256 * kq), dim3(256), 0, stream,
                           x, W, ws, kq_bits, nchunk);
        hipLaunchKernelGGL(pass2, dim3(NT / 128), dim3(128), 0, stream,
                           ws, out, kq, SLAB_OFF);
    }
    hipLaunchKernelGGL(finalize, dim3(1), dim3(64), 0, stream, ws, out);
}